// Round 3
// baseline (823.034 us; speedup 1.0000x reference)
//
#include <hip/hip_runtime.h>
#include <stdint.h>

#define M_DIM 8192
#define N_DIM 4096
#define K_DIM 4096

typedef float f32x4 __attribute__((ext_vector_type(4)));

__device__ __forceinline__ float wave_max(float v) {
#pragma unroll
  for (int off = 32; off > 0; off >>= 1)
    v = fmaxf(v, __shfl_xor(v, off, 64));
  return v;
}

// srelu then 2:4 sparsify: keep top-2 of each group of 4, ties to lower index
// (matches jax.lax.top_k + one_hot mask in the reference).
__device__ __forceinline__ void srelu24(const float4 f, float o[4]) {
  float g0 = fmaxf(f.x, 0.f); g0 *= g0;
  float g1 = fmaxf(f.y, 0.f); g1 *= g1;
  float g2 = fmaxf(f.z, 0.f); g2 *= g2;
  float g3 = fmaxf(f.w, 0.f); g3 *= g3;
  int r0 = (g1 > g0) + (g2 > g0) + (g3 > g0);
  int r1 = (g0 >= g1) + (g2 > g1) + (g3 > g1);
  int r2 = (g0 >= g2) + (g1 >= g2) + (g3 > g2);
  int r3 = (g0 >= g3) + (g1 >= g3) + (g2 >= g3);
  o[0] = (r0 < 2) ? g0 : 0.f;
  o[1] = (r1 < 2) ? g1 : 0.f;
  o[2] = (r2 < 2) ? g2 : 0.f;
  o[3] = (r3 < 2) ? g3 : 0.f;
}

__device__ __forceinline__ uint32_t quant4(const float* v, float scale) {
  int p = 0;
  p = __builtin_amdgcn_cvt_pk_fp8_f32(v[0] / scale, v[1] / scale, p, false);
  p = __builtin_amdgcn_cvt_pk_fp8_f32(v[2] / scale, v[3] / scale, p, true);
  return (uint32_t)p;
}

// ---------------------------------------------------------------------------
// X path: srelu -> 2:4 -> rowwise absmax -> (optionally) fp8 store.
// One block per row, 256 threads x 16 elements.
// ---------------------------------------------------------------------------
template <bool STORE>
__global__ __launch_bounds__(256) void act_quant_kernel(
    const float* __restrict__ x, uint8_t* __restrict__ Xq,
    float* __restrict__ Xs) {
  const int row = blockIdx.x;
  const int t = threadIdx.x;
  const float* xp = x + (size_t)row * K_DIM + t * 16;

  float v[16];
#pragma unroll
  for (int i = 0; i < 4; ++i) srelu24(((const float4*)xp)[i], &v[i * 4]);

  float mx = 0.f;  // nonnegative after relu^2
#pragma unroll
  for (int i = 0; i < 16; ++i) mx = fmaxf(mx, v[i]);
  mx = wave_max(mx);

  __shared__ float red[4];
  if ((t & 63) == 0) red[t >> 6] = mx;
  __syncthreads();
  mx = fmaxf(fmaxf(red[0], red[1]), fmaxf(red[2], red[3]));

  const float scale = fmaxf(mx, 1e-12f) / 448.0f;
  if (t == 0) Xs[row] = scale;

  if constexpr (STORE) {
    uint4 pk;
    pk.x = quant4(&v[0], scale);
    pk.y = quant4(&v[4], scale);
    pk.z = quant4(&v[8], scale);
    pk.w = quant4(&v[12], scale);
    *(uint4*)(Xq + (size_t)row * K_DIM + t * 16) = pk;
  }
}

// ---------------------------------------------------------------------------
// W path: rowwise absmax -> (optionally) fp8 store. One block per row.
// ---------------------------------------------------------------------------
template <bool STORE>
__global__ __launch_bounds__(256) void w_quant_kernel(
    const float* __restrict__ w, uint8_t* __restrict__ Wq,
    float* __restrict__ Ws) {
  const int row = blockIdx.x;
  const int t = threadIdx.x;
  const float* wp = w + (size_t)row * K_DIM + t * 16;

  float v[16];
  float mx = 0.f;
#pragma unroll
  for (int i = 0; i < 4; ++i) {
    float4 f = ((const float4*)wp)[i];
    v[i * 4 + 0] = f.x; v[i * 4 + 1] = f.y;
    v[i * 4 + 2] = f.z; v[i * 4 + 3] = f.w;
    mx = fmaxf(mx, fmaxf(fmaxf(fabsf(f.x), fabsf(f.y)),
                         fmaxf(fabsf(f.z), fabsf(f.w))));
  }
  mx = wave_max(mx);

  __shared__ float red[4];
  if ((t & 63) == 0) red[t >> 6] = mx;
  __syncthreads();
  mx = fmaxf(fmaxf(red[0], red[1]), fmaxf(red[2], red[3]));

  const float scale = fmaxf(mx, 1e-12f) / 448.0f;
  if (t == 0) Ws[row] = scale;

  if constexpr (STORE) {
    uint4 pk;
    pk.x = quant4(&v[0], scale);
    pk.y = quant4(&v[4], scale);
    pk.z = quant4(&v[8], scale);
    pk.w = quant4(&v[12], scale);
    *(uint4*)(Wq + (size_t)row * K_DIM + t * 16) = pk;
  }
}

// ---------------------------------------------------------------------------
// fp8 GEMM, m97 structure: 128x128 tile, BK=64, 4 waves (2x2), 4x4
// mfma_f32_16x16x32_fp8_fp8 per wave.
// AM/BM: 0 = operand pre-quantized in ws (global_load_lds staging);
//        1 = fused on-the-fly quant from f32 (reg stage + ds_write).
// ---------------------------------------------------------------------------
__device__ __forceinline__ void g2l16(const uint8_t* g, uint8_t* l) {
  __builtin_amdgcn_global_load_lds(
      (const __attribute__((address_space(1))) void*)g,
      (__attribute__((address_space(3))) void*)l, 16, 0, 0);
}

template <int AM, int BM>
__global__ __launch_bounds__(256) void gemm_kernel(
    const uint8_t* __restrict__ Xq, const uint8_t* __restrict__ Wq,
    const float* __restrict__ xf, const float* __restrict__ wf,
    const float* __restrict__ Xs, const float* __restrict__ Ws,
    float* __restrict__ out) {
  __shared__ __align__(16) uint8_t As[128 * 64];
  __shared__ __align__(16) uint8_t Bs[128 * 64];

  const int tid = threadIdx.x;
  const int lane = tid & 63;
  const int wid = tid >> 6;
  const int wm = wid >> 1;
  const int wn = wid & 1;
  const int tn = blockIdx.x * 128;
  const int tm = blockIdx.y * 128;

  f32x4 acc[4][4] = {};

  // prequant staging: thread t -> row tid>>2, 16B chunk (tid&3)*16
  const int sr = tid >> 2;
  const int sc = (tid & 3) * 16;
  const uint8_t* gA = (AM == 0) ? Xq + (size_t)(tm + sr) * K_DIM + sc : nullptr;
  const uint8_t* gB = (BM == 0) ? Wq + (size_t)(tn + sr) * K_DIM + sc : nullptr;
  uint8_t* lA = As + tid * 16;
  uint8_t* lB = Bs + tid * 16;

  // fused staging: thread t -> row tid>>1, 32-col half (tid&1)*32
  const int fr = tid >> 1;
  const int fc = (tid & 1) * 32;
  float sA = 0.f, sB = 0.f;
  if (AM == 1) sA = Xs[tm + fr];
  if (BM == 1) sB = Ws[tn + fr];

  // fragment offsets in LDS (row stride 64B)
  const int afrag = (wm * 64 + (lane & 15)) * 64 + (lane >> 4) * 8;
  const int bfrag = (wn * 64 + (lane & 15)) * 64 + (lane >> 4) * 8;

  for (int kt = 0; kt < K_DIM / 64; ++kt) {
    const int k0 = kt * 64;
    if (AM == 0) {
      g2l16(gA + k0, lA);
      g2l16(gA + k0 + (size_t)64 * K_DIM, lA + 4096);
    } else {
      const float* src = xf + (size_t)(tm + fr) * K_DIM + k0 + fc;
      uint32_t pk[8];
#pragma unroll
      for (int i = 0; i < 8; ++i) {
        float o[4];
        srelu24(((const float4*)src)[i], o);
        pk[i] = quant4(o, sA);
      }
      *(uint4*)(As + fr * 64 + fc) = make_uint4(pk[0], pk[1], pk[2], pk[3]);
      *(uint4*)(As + fr * 64 + fc + 16) = make_uint4(pk[4], pk[5], pk[6], pk[7]);
    }
    if (BM == 0) {
      g2l16(gB + k0, lB);
      g2l16(gB + k0 + (size_t)64 * K_DIM, lB + 4096);
    } else {
      const float* src = wf + (size_t)(tn + fr) * K_DIM + k0 + fc;
      uint32_t pk[8];
#pragma unroll
      for (int i = 0; i < 8; ++i) {
        float4 f = ((const float4*)src)[i];
        float o[4] = {f.x, f.y, f.z, f.w};
        pk[i] = quant4(o, sB);
      }
      *(uint4*)(Bs + fr * 64 + fc) = make_uint4(pk[0], pk[1], pk[2], pk[3]);
      *(uint4*)(Bs + fr * 64 + fc + 16) = make_uint4(pk[4], pk[5], pk[6], pk[7]);
    }
    __syncthreads();  // drains vmcnt+lgkmcnt: tile fully staged

#pragma unroll
    for (int ks = 0; ks < 2; ++ks) {
      long av[4], bv[4];
#pragma unroll
      for (int f = 0; f < 4; ++f)
        av[f] = *(const long*)(As + afrag + f * 16 * 64 + ks * 32);
#pragma unroll
      for (int f = 0; f < 4; ++f)
        bv[f] = *(const long*)(Bs + bfrag + f * 16 * 64 + ks * 32);
#pragma unroll
      for (int mf = 0; mf < 4; ++mf)
#pragma unroll
        for (int nf = 0; nf < 4; ++nf)
          acc[mf][nf] = __builtin_amdgcn_mfma_f32_16x16x32_fp8_fp8(
              av[mf], bv[nf], acc[mf][nf], 0, 0, 0);
    }
    __syncthreads();  // reads done before next stage overwrites
  }

  // C/D layout: col = lane&15 (N), row = (lane>>4)*4 + i (M)
#pragma unroll
  for (int nf = 0; nf < 4; ++nf) {
    const int n = tn + wn * 64 + nf * 16 + (lane & 15);
    const float wsc = Ws[n];
#pragma unroll
    for (int mf = 0; mf < 4; ++mf) {
      const int mb = tm + wm * 64 + mf * 16 + (lane >> 4) * 4;
#pragma unroll
      for (int i = 0; i < 4; ++i) {
        const int m = mb + i;
        out[(size_t)m * N_DIM + n] = acc[mf][nf][i] * Xs[m] * wsc;
      }
    }
  }
}

extern "C" void kernel_launch(void* const* d_in, const int* in_sizes, int n_in,
                              void* d_out, int out_size, void* d_ws,
                              size_t ws_size, hipStream_t stream) {
  const float* x = (const float*)d_in[0];  // [8192,4096] f32
  const float* w = (const float*)d_in[1];  // [4096,4096] f32
  float* out = (float*)d_out;              // [8192,4096] f32

  // ws layout: scales first (tiny), quant buffers after — and ONLY if they fit.
  uint8_t* ws = (uint8_t*)d_ws;
  float* Xs = (float*)ws;                  // 32 KB
  float* Wsc = Xs + M_DIM;                 // 16 KB
  uint8_t* qbase = ws + 49152;
  const size_t XQ_BYTES = (size_t)M_DIM * K_DIM;  // 32 MB
  const size_t WQ_BYTES = (size_t)N_DIM * K_DIM;  // 16 MB
  const size_t REQ_A = 49152 + XQ_BYTES + WQ_BYTES;
  const size_t REQ_B = 49152 + WQ_BYTES;

  dim3 ggrid(N_DIM / 128, M_DIM / 128);
  if (ws_size >= REQ_A) {
    uint8_t* Xq = qbase;
    uint8_t* Wq = qbase + XQ_BYTES;
    act_quant_kernel<true><<<M_DIM, 256, 0, stream>>>(x, Xq, Xs);
    w_quant_kernel<true><<<N_DIM, 256, 0, stream>>>(w, Wq, Wsc);
    gemm_kernel<0, 0><<<ggrid, 256, 0, stream>>>(Xq, Wq, x, w, Xs, Wsc, out);
  } else if (ws_size >= REQ_B) {
    uint8_t* Wq = qbase;
    act_quant_kernel<false><<<M_DIM, 256, 0, stream>>>(x, nullptr, Xs);
    w_quant_kernel<true><<<N_DIM, 256, 0, stream>>>(w, Wq, Wsc);
    gemm_kernel<1, 0><<<ggrid, 256, 0, stream>>>(nullptr, Wq, x, w, Xs, Wsc,
                                                 out);
  } else {
    act_quant_kernel<false><<<M_DIM, 256, 0, stream>>>(x, nullptr, Xs);
    w_quant_kernel<false><<<N_DIM, 256, 0, stream>>>(w, nullptr, Wsc);
    gemm_kernel<1, 1><<<ggrid, 256, 0, stream>>>(nullptr, nullptr, x, w, Xs,
                                                 Wsc, out);
  }
}

// Round 4
// 498.580 us; speedup vs baseline: 1.6508x; 1.6508x over previous
//
#include <hip/hip_runtime.h>
#include <stdint.h>

#define M_DIM 8192
#define N_DIM 4096
#define K_DIM 4096
#define NT 64  // K tiles of 64 fp8 bytes

typedef float f32x4 __attribute__((ext_vector_type(4)));

__device__ __forceinline__ float wave_max(float v) {
#pragma unroll
  for (int off = 32; off > 0; off >>= 1)
    v = fmaxf(v, __shfl_xor(v, off, 64));
  return v;
}

// srelu then 2:4 sparsify: keep top-2 of each group of 4, ties to lower index
// (matches jax.lax.top_k + one_hot mask in the reference).
__device__ __forceinline__ void srelu24(const float4 f, float o[4]) {
  float g0 = fmaxf(f.x, 0.f); g0 *= g0;
  float g1 = fmaxf(f.y, 0.f); g1 *= g1;
  float g2 = fmaxf(f.z, 0.f); g2 *= g2;
  float g3 = fmaxf(f.w, 0.f); g3 *= g3;
  int r0 = (g1 > g0) + (g2 > g0) + (g3 > g0);
  int r1 = (g0 >= g1) + (g2 > g1) + (g3 > g1);
  int r2 = (g0 >= g2) + (g1 >= g2) + (g3 > g2);
  int r3 = (g0 >= g3) + (g1 >= g3) + (g2 >= g3);
  o[0] = (r0 < 2) ? g0 : 0.f;
  o[1] = (r1 < 2) ? g1 : 0.f;
  o[2] = (r2 < 2) ? g2 : 0.f;
  o[3] = (r3 < 2) ? g3 : 0.f;
}

__device__ __forceinline__ uint32_t quant4(const float* v, float scale) {
  int p = 0;
  p = __builtin_amdgcn_cvt_pk_fp8_f32(v[0] / scale, v[1] / scale, p, false);
  p = __builtin_amdgcn_cvt_pk_fp8_f32(v[2] / scale, v[3] / scale, p, true);
  return (uint32_t)p;
}

__device__ __forceinline__ void g2l16(const uint8_t* g, uint8_t* l) {
  __builtin_amdgcn_global_load_lds(
      (const __attribute__((address_space(1))) void*)g,
      (__attribute__((address_space(3))) void*)l, 16, 0, 0);
}

// ---------------------------------------------------------------------------
// TIER A quant kernels: write fp8 into BLOB layout = the exact LDS image the
// GEMM stages linearly. Blob = 128 rows x 64B (8KB), one per (row-half, kt).
// Within a blob, byte (r, c) is stored at (r, c ^ ((r&7)<<3))  [bank swizzle].
// A-blobs: Xq[(mhalf*NT + kt)*8192], mhalf = m>>7.  B-blobs likewise for W.
// Coalesced lane-contiguous float4 loads (fix of the 1 TB/s round-3 pattern).
// ---------------------------------------------------------------------------
__global__ __launch_bounds__(256) void act_quant_blob(
    const float* __restrict__ x, uint8_t* __restrict__ Xq,
    float* __restrict__ Xs) {
  const int m = blockIdx.x;
  const int t = threadIdx.x;
  const float4* xp = (const float4*)(x + (size_t)m * K_DIM);

  float o[4][4];
  float mx = 0.f;  // nonnegative after relu^2
#pragma unroll
  for (int i = 0; i < 4; ++i) {
    float4 f = xp[i * 256 + t];  // lane-contiguous 16B -> coalesced
    srelu24(f, o[i]);
    mx = fmaxf(mx, fmaxf(fmaxf(o[i][0], o[i][1]), fmaxf(o[i][2], o[i][3])));
  }
  mx = wave_max(mx);
  __shared__ float red[4];
  if ((t & 63) == 0) red[t >> 6] = mx;
  __syncthreads();
  mx = fmaxf(fmaxf(red[0], red[1]), fmaxf(red[2], red[3]));
  const float scale = fmaxf(mx, 1e-12f) / 448.0f;
  if (t == 0) Xs[m] = scale;

  const int r = m & 127;
  const int mhalf = m >> 7;
  const int swz = (r & 7) << 3;
#pragma unroll
  for (int i = 0; i < 4; ++i) {
    const int g = i * 256 + t;          // group of 4 elements
    const int kt = g >> 4;              // 16 groups (64B) per K-tile
    const int c = (g & 15) * 4;         // logical byte col in tile row
    uint8_t* dst =
        Xq + ((size_t)(mhalf * NT + kt)) * 8192 + r * 64 + (c ^ swz);
    *(uint32_t*)dst = quant4(o[i], scale);
  }
}

__global__ __launch_bounds__(256) void w_quant_blob(
    const float* __restrict__ w, uint8_t* __restrict__ Wq,
    float* __restrict__ Ws) {
  const int n = blockIdx.x;
  const int t = threadIdx.x;
  const float4* wp = (const float4*)(w + (size_t)n * K_DIM);

  float o[4][4];
  float mx = 0.f;
#pragma unroll
  for (int i = 0; i < 4; ++i) {
    float4 f = wp[i * 256 + t];
    o[i][0] = f.x; o[i][1] = f.y; o[i][2] = f.z; o[i][3] = f.w;
    mx = fmaxf(mx, fmaxf(fmaxf(fabsf(f.x), fabsf(f.y)),
                         fmaxf(fabsf(f.z), fabsf(f.w))));
  }
  mx = wave_max(mx);
  __shared__ float red[4];
  if ((t & 63) == 0) red[t >> 6] = mx;
  __syncthreads();
  mx = fmaxf(fmaxf(red[0], red[1]), fmaxf(red[2], red[3]));
  const float scale = fmaxf(mx, 1e-12f) / 448.0f;
  if (t == 0) Ws[n] = scale;

  const int r = n & 127;
  const int nhalf = n >> 7;
  const int swz = (r & 7) << 3;
#pragma unroll
  for (int i = 0; i < 4; ++i) {
    const int g = i * 256 + t;
    const int kt = g >> 4;
    const int c = (g & 15) * 4;
    uint8_t* dst =
        Wq + ((size_t)(nhalf * NT + kt)) * 8192 + r * 64 + (c ^ swz);
    *(uint32_t*)dst = quant4(o[i], scale);
  }
}

// ---------------------------------------------------------------------------
// TIER A GEMM: 256x256 tile, BK=64B, 8 waves (2M x 4N), 8-phase schedule with
// 4-buffer LDS rotation, counted vmcnt(8), setprio around MFMA (T3+T4+T5).
// Blob layout makes staging linear (global_load_lds 16B) and fragment
// ds_read_b64 bank-minimal (4 accesses/bank, uniform).
// Buffer invariant: tile j lives in buf j%4; iter(kt): phases 0-3 compute kt
// and stage kt+3 -> buf (kt+3)%4 (read-free since prev iter); phases 4-7
// compute kt+1 and stage kt+4 -> buf kt%4 (reads done at phase 3).
// vmcnt(8) at end of phases 3 and 7 retires exactly the tile needed next.
// ---------------------------------------------------------------------------
__global__ __launch_bounds__(512) void gemm8_kernel(
    const uint8_t* __restrict__ Ab, const uint8_t* __restrict__ Bb,
    const float* __restrict__ Xs, const float* __restrict__ Ws,
    float* __restrict__ out) {
  __shared__ __align__(16) uint8_t lds[131072];
  const int tid = threadIdx.x;
  const int lane = tid & 63;
  const int wid = tid >> 6;  // 0..7
  const int wm = wid >> 2;   // 0..1 (M half)
  const int wn = wid & 3;    // 0..3 (N quarter)

  // XCD-aware swizzle (512 blocks, 512%8==0 -> simple form is bijective)
  const int bid = blockIdx.x;
  const int swb = (bid & 7) * 64 + (bid >> 3);
  const int by = swb & 31;   // 32 M-blocks
  const int bx = swb >> 5;   // 16 N-blocks
  const int tm = by * 256, tn = bx * 256;

  const int l15 = lane & 15;
  // per-thread swizzled k-offset: logical col (lane>>4)*8, XOR'd by row key
  const int v = ((lane >> 4) * 8) ^ ((lane & 7) << 3);
  const int aoff0 = wm * 8192 + l15 * 64 + v;
  const int aoff1 = aoff0 ^ 32;  // ks=1 flips byte-bit 5
  const int boff0 = 16384 + (wn >> 1) * 8192 + (wn & 1) * 4096 + l15 * 64 + v;
  const int boff1 = boff0 ^ 32;

  f32x4 acc[8][4] = {};

#define STAGE(BUF, OP, H, TILE)                                              \
  do {                                                                       \
    const int _panel = (OP == 0) ? (by * 2 + (H)) : (bx * 2 + (H));          \
    const uint8_t* _src = ((OP == 0) ? Ab : Bb) +                            \
                          ((size_t)(_panel * NT + (TILE))) * 8192 + tid * 16;\
    uint8_t* _dst = lds + (BUF) * 32768 + (OP) * 16384 + (H) * 8192 +        \
                    tid * 16;                                                \
    g2l16(_src, _dst);                                                       \
  } while (0)

  // prologue: fill bufs 0..2 with tiles 0..2 (12 loads in flight)
  for (int tp = 0; tp < 3; ++tp) {
    STAGE(tp, 0, 0, tp);
    STAGE(tp, 0, 1, tp);
    STAGE(tp, 1, 0, tp);
    STAGE(tp, 1, 1, tp);
  }
  asm volatile("s_waitcnt vmcnt(8)" ::: "memory");  // tile 0 landed
  __builtin_amdgcn_s_barrier();

  for (int kt = 0; kt < NT; kt += 2) {
    const int pa = kt & 3, pb = (kt + 1) & 3;
    const int s3 = (kt + 3) & 3, s4 = kt & 3;
    const int t3 = (kt + 3 < NT) ? kt + 3 : NT - 1;  // clamp keeps pipeline
    const int t4 = (kt + 4 < NT) ? kt + 4 : NT - 1;  // shape uniform at tail

#pragma unroll
    for (int p = 0; p < 8; ++p) {
      const int s = p >> 2;   // 0: tile kt, 1: tile kt+1
      const int q = p & 3;
      const int mh = q >> 1;  // M-half of this wave's 8 mf frags
      const int ks = q & 1;   // k-slice within 64B tile
      const int buf = s ? pb : pa;
      const uint8_t* base = lds + buf * 32768;
      const int ao = ks ? aoff1 : aoff0;
      const int bo = ks ? boff1 : boff0;

      long a[4], b[4];
#pragma unroll
      for (int f = 0; f < 4; ++f)
        a[f] = *(const long*)(base + ao + (mh * 4 + f) * 1024);
#pragma unroll
      for (int f = 0; f < 4; ++f)
        b[f] = *(const long*)(base + bo + f * 1024);

      // stage one half-tile: phases 0-3 -> tile kt+3, phases 4-7 -> kt+4
      if (s == 0) STAGE(s3, (q >> 1), (q & 1), t3);
      else        STAGE(s4, (q >> 1), (q & 1), t4);

      __builtin_amdgcn_s_barrier();
      asm volatile("s_waitcnt lgkmcnt(0)" ::: "memory");
      __builtin_amdgcn_sched_barrier(0);  // rule #18: pin MFMA after the wait
      __builtin_amdgcn_s_setprio(1);
#pragma unroll
      for (int f = 0; f < 4; ++f)
#pragma unroll
        for (int nf = 0; nf < 4; ++nf)
          acc[mh * 4 + f][nf] = __builtin_amdgcn_mfma_f32_16x16x32_fp8_fp8(
              a[f], b[nf], acc[mh * 4 + f][nf], 0, 0, 0);
      __builtin_amdgcn_s_setprio(0);
      if (q == 3)  // once per K-tile; retires exactly the next-needed tile
        asm volatile("s_waitcnt vmcnt(8)" ::: "memory");
      __builtin_amdgcn_s_barrier();
    }
  }
#undef STAGE

  // epilogue: C/D col = lane&15 (N), row = (lane>>4)*4 + i (M)
  float wsn[4];
#pragma unroll
  for (int nf = 0; nf < 4; ++nf) wsn[nf] = Ws[tn + wn * 64 + nf * 16 + l15];
#pragma unroll
  for (int mf = 0; mf < 8; ++mf) {
    const int mb = tm + wm * 128 + mf * 16 + (lane >> 4) * 4;
    const float4 xs4 = *(const float4*)(Xs + mb);
#pragma unroll
    for (int nf = 0; nf < 4; ++nf) {
      const int n = tn + wn * 64 + nf * 16 + l15;
#pragma unroll
      for (int i = 0; i < 4; ++i) {
        out[(size_t)(mb + i) * N_DIM + n] =
            acc[mf][nf][i] * ((const float*)&xs4)[i] * wsn[nf];
      }
    }
  }
}

// ---------------------------------------------------------------------------
// Fallback (Tier B/C) kernels — round-3 validated path, linear layouts.
// ---------------------------------------------------------------------------
template <bool STORE>
__global__ __launch_bounds__(256) void act_quant_kernel(
    const float* __restrict__ x, uint8_t* __restrict__ Xq,
    float* __restrict__ Xs) {
  const int row = blockIdx.x;
  const int t = threadIdx.x;
  const float* xp = x + (size_t)row * K_DIM + t * 16;

  float v[16];
#pragma unroll
  for (int i = 0; i < 4; ++i) srelu24(((const float4*)xp)[i], &v[i * 4]);

  float mx = 0.f;
#pragma unroll
  for (int i = 0; i < 16; ++i) mx = fmaxf(mx, v[i]);
  mx = wave_max(mx);
  __shared__ float red[4];
  if ((t & 63) == 0) red[t >> 6] = mx;
  __syncthreads();
  mx = fmaxf(fmaxf(red[0], red[1]), fmaxf(red[2], red[3]));
  const float scale = fmaxf(mx, 1e-12f) / 448.0f;
  if (t == 0) Xs[row] = scale;

  if constexpr (STORE) {
    uint4 pk;
    pk.x = quant4(&v[0], scale);
    pk.y = quant4(&v[4], scale);
    pk.z = quant4(&v[8], scale);
    pk.w = quant4(&v[12], scale);
    *(uint4*)(Xq + (size_t)row * K_DIM + t * 16) = pk;
  }
}

template <bool STORE>
__global__ __launch_bounds__(256) void w_quant_kernel(
    const float* __restrict__ w, uint8_t* __restrict__ Wq,
    float* __restrict__ Ws) {
  const int row = blockIdx.x;
  const int t = threadIdx.x;
  const float* wp = w + (size_t)row * K_DIM + t * 16;

  float v[16];
  float mx = 0.f;
#pragma unroll
  for (int i = 0; i < 4; ++i) {
    float4 f = ((const float4*)wp)[i];
    v[i * 4 + 0] = f.x; v[i * 4 + 1] = f.y;
    v[i * 4 + 2] = f.z; v[i * 4 + 3] = f.w;
    mx = fmaxf(mx, fmaxf(fmaxf(fabsf(f.x), fabsf(f.y)),
                         fmaxf(fabsf(f.z), fabsf(f.w))));
  }
  mx = wave_max(mx);
  __shared__ float red[4];
  if ((t & 63) == 0) red[t >> 6] = mx;
  __syncthreads();
  mx = fmaxf(fmaxf(red[0], red[1]), fmaxf(red[2], red[3]));
  const float scale = fmaxf(mx, 1e-12f) / 448.0f;
  if (t == 0) Ws[row] = scale;

  if constexpr (STORE) {
    uint4 pk;
    pk.x = quant4(&v[0], scale);
    pk.y = quant4(&v[4], scale);
    pk.z = quant4(&v[8], scale);
    pk.w = quant4(&v[12], scale);
    *(uint4*)(Wq + (size_t)row * K_DIM + t * 16) = pk;
  }
}

template <int AM, int BM>
__global__ __launch_bounds__(256) void gemm_kernel(
    const uint8_t* __restrict__ Xq, const uint8_t* __restrict__ Wq,
    const float* __restrict__ xf, const float* __restrict__ wf,
    const float* __restrict__ Xs, const float* __restrict__ Ws,
    float* __restrict__ out) {
  __shared__ __align__(16) uint8_t As[128 * 64];
  __shared__ __align__(16) uint8_t Bs[128 * 64];

  const int tid = threadIdx.x;
  const int lane = tid & 63;
  const int wid = tid >> 6;
  const int wm = wid >> 1;
  const int wn = wid & 1;
  const int tn = blockIdx.x * 128;
  const int tm = blockIdx.y * 128;

  f32x4 acc[4][4] = {};

  const int sr = tid >> 2;
  const int sc = (tid & 3) * 16;
  const uint8_t* gA = (AM == 0) ? Xq + (size_t)(tm + sr) * K_DIM + sc : nullptr;
  const uint8_t* gB = (BM == 0) ? Wq + (size_t)(tn + sr) * K_DIM + sc : nullptr;
  uint8_t* lA = As + tid * 16;
  uint8_t* lB = Bs + tid * 16;

  const int fr = tid >> 1;
  const int fc = (tid & 1) * 32;
  float sA = 0.f, sB = 0.f;
  if (AM == 1) sA = Xs[tm + fr];
  if (BM == 1) sB = Ws[tn + fr];

  const int afrag = (wm * 64 + (lane & 15)) * 64 + (lane >> 4) * 8;
  const int bfrag = (wn * 64 + (lane & 15)) * 64 + (lane >> 4) * 8;

  for (int kt = 0; kt < K_DIM / 64; ++kt) {
    const int k0 = kt * 64;
    if (AM == 0) {
      g2l16(gA + k0, lA);
      g2l16(gA + k0 + (size_t)64 * K_DIM, lA + 4096);
    } else {
      const float* src = xf + (size_t)(tm + fr) * K_DIM + k0 + fc;
      uint32_t pk[8];
#pragma unroll
      for (int i = 0; i < 8; ++i) {
        float o[4];
        srelu24(((const float4*)src)[i], o);
        pk[i] = quant4(o, sA);
      }
      *(uint4*)(As + fr * 64 + fc) = make_uint4(pk[0], pk[1], pk[2], pk[3]);
      *(uint4*)(As + fr * 64 + fc + 16) = make_uint4(pk[4], pk[5], pk[6], pk[7]);
    }
    if (BM == 0) {
      g2l16(gB + k0, lB);
      g2l16(gB + k0 + (size_t)64 * K_DIM, lB + 4096);
    } else {
      const float* src = wf + (size_t)(tn + fr) * K_DIM + k0 + fc;
      uint32_t pk[8];
#pragma unroll
      for (int i = 0; i < 8; ++i) {
        float4 f = ((const float4*)src)[i];
        float o[4] = {f.x, f.y, f.z, f.w};
        pk[i] = quant4(o, sB);
      }
      *(uint4*)(Bs + fr * 64 + fc) = make_uint4(pk[0], pk[1], pk[2], pk[3]);
      *(uint4*)(Bs + fr * 64 + fc + 16) = make_uint4(pk[4], pk[5], pk[6], pk[7]);
    }
    __syncthreads();

#pragma unroll
    for (int ks = 0; ks < 2; ++ks) {
      long av[4], bv[4];
#pragma unroll
      for (int f = 0; f < 4; ++f)
        av[f] = *(const long*)(As + afrag + f * 16 * 64 + ks * 32);
#pragma unroll
      for (int f = 0; f < 4; ++f)
        bv[f] = *(const long*)(Bs + bfrag + f * 16 * 64 + ks * 32);
#pragma unroll
      for (int mf = 0; mf < 4; ++mf)
#pragma unroll
        for (int nf = 0; nf < 4; ++nf)
          acc[mf][nf] = __builtin_amdgcn_mfma_f32_16x16x32_fp8_fp8(
              av[mf], bv[nf], acc[mf][nf], 0, 0, 0);
    }
    __syncthreads();
  }

#pragma unroll
  for (int nf = 0; nf < 4; ++nf) {
    const int n = tn + wn * 64 + nf * 16 + (lane & 15);
    const float wsc = Ws[n];
#pragma unroll
    for (int mf = 0; mf < 4; ++mf) {
      const int mb = tm + wm * 64 + mf * 16 + (lane >> 4) * 4;
#pragma unroll
      for (int i = 0; i < 4; ++i) {
        const int m = mb + i;
        out[(size_t)m * N_DIM + n] = acc[mf][nf][i] * Xs[m] * wsc;
      }
    }
  }
}

extern "C" void kernel_launch(void* const* d_in, const int* in_sizes, int n_in,
                              void* d_out, int out_size, void* d_ws,
                              size_t ws_size, hipStream_t stream) {
  const float* x = (const float*)d_in[0];  // [8192,4096] f32
  const float* w = (const float*)d_in[1];  // [4096,4096] f32
  float* out = (float*)d_out;              // [8192,4096] f32

  uint8_t* ws = (uint8_t*)d_ws;
  float* Xs = (float*)ws;                  // 32 KB
  float* Wsc = Xs + M_DIM;                 // 16 KB
  uint8_t* qbase = ws + 49152;
  const size_t XQ_BYTES = (size_t)M_DIM * K_DIM;  // 32 MB
  const size_t WQ_BYTES = (size_t)N_DIM * K_DIM;  // 16 MB
  const size_t REQ_A = 49152 + XQ_BYTES + WQ_BYTES;
  const size_t REQ_B = 49152 + WQ_BYTES;

  if (ws_size >= REQ_A) {
    uint8_t* Xq = qbase;                   // blob layout
    uint8_t* Wq = qbase + XQ_BYTES;        // blob layout
    act_quant_blob<<<M_DIM, 256, 0, stream>>>(x, Xq, Xs);
    w_quant_blob<<<N_DIM, 256, 0, stream>>>(w, Wq, Wsc);
    gemm8_kernel<<<512, 512, 0, stream>>>(Xq, Wq, Xs, Wsc, out);
  } else if (ws_size >= REQ_B) {
    uint8_t* Wq = qbase;                   // linear layout
    act_quant_kernel<false><<<M_DIM, 256, 0, stream>>>(x, nullptr, Xs);
    w_quant_kernel<true><<<N_DIM, 256, 0, stream>>>(w, Wq, Wsc);
    gemm_kernel<1, 0><<<dim3(N_DIM / 128, M_DIM / 128), 256, 0, stream>>>(
        nullptr, Wq, x, w, Xs, Wsc, out);
  } else {
    act_quant_kernel<false><<<M_DIM, 256, 0, stream>>>(x, nullptr, Xs);
    w_quant_kernel<false><<<N_DIM, 256, 0, stream>>>(w, nullptr, Wsc);
    gemm_kernel<1, 1><<<dim3(N_DIM / 128, M_DIM / 128), 256, 0, stream>>>(
        nullptr, nullptr, x, w, Xs, Wsc, out);
  }
}